// Round 1
// baseline (832829.102 us; speedup 1.0000x reference)
//
#include <hip/hip_runtime.h>
#include <hip/hip_bf16.h>
#include <math.h>

// Sizes
#define N_NODES 8192
#define IN_DIM 64
#define MLP_HID 128
#define EMB 512
#define HID 1024
#define G3 (3*HID)   // 3072
#define SEQ 8192

// ---------------------------------------------------------------------------
// Expert MLP: one block per node. h1 = relu(x@W1[t]+b1[t]); emb = h1@W2[t]+b2[t]
// ---------------------------------------------------------------------------
__global__ __launch_bounds__(256) void mlp_kernel(
    const float* __restrict__ x, const int* __restrict__ types,
    const float* __restrict__ W1, const float* __restrict__ b1,
    const float* __restrict__ W2, const float* __restrict__ b2,
    float* __restrict__ emb)
{
    __shared__ float xs[IN_DIM];
    __shared__ float h1[MLP_HID];
    const int n = blockIdx.x;
    const int ty = types[n];
    const int tid = threadIdx.x;

    if (tid < IN_DIM) xs[tid] = x[n * IN_DIM + tid];
    __syncthreads();

    if (tid < MLP_HID) {
        const float* w = W1 + (size_t)ty * IN_DIM * MLP_HID;
        float acc = b1[ty * MLP_HID + tid];
        #pragma unroll 8
        for (int k = 0; k < IN_DIM; k++)
            acc += xs[k] * w[k * MLP_HID + tid];
        h1[tid] = fmaxf(acc, 0.f);
    }
    __syncthreads();

    const float* w2 = W2 + (size_t)ty * MLP_HID * EMB;
    #pragma unroll
    for (int j = tid; j < EMB; j += 256) {
        float acc = b2[ty * EMB + j];
        #pragma unroll 8
        for (int k = 0; k < MLP_HID; k++)
            acc += h1[k] * w2[k * EMB + j];
        emb[(size_t)n * EMB + j] = acc;
    }
}

// ---------------------------------------------------------------------------
// C[M,N] = A[M,K] @ B[N,K]^T + bias[N]   (fp32, 64x64 tile, BK=16)
// ---------------------------------------------------------------------------
#define BM 64
#define BN 64
#define BK 16
__global__ __launch_bounds__(256) void gemm_bt_bias(
    const float* __restrict__ A, const float* __restrict__ B,
    const float* __restrict__ bias, float* __restrict__ C,
    int M, int N, int K)
{
    __shared__ float As[BK][BM + 1];
    __shared__ float Bs[BK][BN + 1];
    const int bm = blockIdx.y * BM, bn = blockIdx.x * BN;
    const int tid = threadIdx.x;
    const int tx = tid & 15, tyy = tid >> 4;   // 16x16 thread grid
    const int lr = tid >> 2;                   // loader row 0..63
    const int lk = (tid & 3) * 4;              // loader k offset

    float acc[4][4] = {};

    for (int k0 = 0; k0 < K; k0 += BK) {
        float4 av = *(const float4*)(A + (size_t)(bm + lr) * K + k0 + lk);
        float4 bv = *(const float4*)(B + (size_t)(bn + lr) * K + k0 + lk);
        As[lk + 0][lr] = av.x; As[lk + 1][lr] = av.y;
        As[lk + 2][lr] = av.z; As[lk + 3][lr] = av.w;
        Bs[lk + 0][lr] = bv.x; Bs[lk + 1][lr] = bv.y;
        Bs[lk + 2][lr] = bv.z; Bs[lk + 3][lr] = bv.w;
        __syncthreads();
        #pragma unroll
        for (int k = 0; k < BK; k++) {
            float a[4], b[4];
            #pragma unroll
            for (int i = 0; i < 4; i++) a[i] = As[k][tyy * 4 + i];
            #pragma unroll
            for (int j = 0; j < 4; j++) b[j] = Bs[k][tx * 4 + j];
            #pragma unroll
            for (int i = 0; i < 4; i++)
                #pragma unroll
                for (int j = 0; j < 4; j++)
                    acc[i][j] += a[i] * b[j];
        }
        __syncthreads();
    }

    #pragma unroll
    for (int i = 0; i < 4; i++) {
        const int row = bm + tyy * 4 + i;
        #pragma unroll
        for (int j = 0; j < 4; j++) {
            const int col = bn + tx * 4 + j;
            C[(size_t)row * N + col] = acc[i][j] + bias[col];
        }
    }
}

// ---------------------------------------------------------------------------
// GRU scan: persistent grid of 256 blocks, block b owns h-dims [4b, 4b+4).
// Per step: barrier-exchanged h (agent-scope atomics), 12 LDS-resident Whh
// rows dotted against h, gates, write h_new + y.
// flags: 1024 slots (one per (block,wave)), each padded to 32 ints (128 B).
// ---------------------------------------------------------------------------
__global__ __launch_bounds__(256) void gru_scan(
    const float* __restrict__ gi,    // [T, 3072]
    const float* __restrict__ Whh,   // [3072, 1024]
    const float* __restrict__ bhh,   // [3072]
    const float* __restrict__ h0,    // [1024]
    float* __restrict__ hA, float* __restrict__ hB,
    float* __restrict__ y,           // [T, 1024]
    int* __restrict__ flags,
    int T)
{
    __shared__ float wlds[12 * HID];
    __shared__ float hl[HID];

    const int tid = threadIdx.x;
    const int b = blockIdx.x;
    const int wv = tid >> 6;
    const int lane = tid & 63;
    const int d = b * 4 + wv;

    // Stage this block's 12 Whh rows into LDS. Local row lr = wv*3 + gate.
    for (int idx = tid; idx < 12 * HID; idx += 256) {
        const int lrow = idx >> 10, col = idx & (HID - 1);
        const int dl = lrow / 3, g = lrow % 3;
        const int grow = g * HID + (b * 4 + dl);
        wlds[idx] = Whh[(size_t)grow * HID + col];
    }
    const float bhr = bhh[d];
    const float bhz = bhh[HID + d];
    const float bhn = bhh[2 * HID + d];
    __syncthreads();

    for (int t = 0; t < T; t++) {
        const float* hsrc = (t == 0) ? h0 : ((t & 1) ? hA : hB);
        float* hdst = (t & 1) ? hB : hA;

        // Pull full h into LDS (agent-scope coherent loads).
        #pragma unroll
        for (int j = 0; j < 4; j++)
            hl[tid * 4 + j] = __hip_atomic_load(&hsrc[tid * 4 + j],
                                                __ATOMIC_RELAXED, __HIP_MEMORY_SCOPE_AGENT);
        __syncthreads();

        float hreg[16];
        #pragma unroll
        for (int u = 0; u < 16; u++) hreg[u] = hl[lane + 64 * u];

        float s[3];
        #pragma unroll
        for (int g = 0; g < 3; g++) {
            const float* wr = &wlds[(wv * 3 + g) * HID];
            float acc = 0.f;
            #pragma unroll
            for (int u = 0; u < 16; u++)
                acc += wr[lane + 64 * u] * hreg[u];
            #pragma unroll
            for (int off = 32; off; off >>= 1)
                acc += __shfl_down(acc, off, 64);
            s[g] = acc;
        }

        if (lane == 0) {
            const float* git = gi + (size_t)t * G3;
            const float ir = git[d], iz = git[HID + d], inn = git[2 * HID + d];
            const float gr = s[0] + bhr, gz = s[1] + bhz, gn = s[2] + bhn;
            const float r = 1.f / (1.f + expf(-(ir + gr)));
            const float z = 1.f / (1.f + expf(-(iz + gz)));
            const float nn = tanhf(inn + r * gn);
            const float hprev = hl[d];
            const float hnew = (1.f - z) * nn + z * hprev;
            __hip_atomic_store(&hdst[d], hnew, __ATOMIC_RELAXED, __HIP_MEMORY_SCOPE_AGENT);
            y[(size_t)t * HID + d] = hnew;
            // release: orders the h/y stores before the flag
            __hip_atomic_store(&flags[d * 32], t + 1,
                               __ATOMIC_RELEASE, __HIP_MEMORY_SCOPE_AGENT);
        }

        // Flat barrier: every thread polls 4 of the 1024 writer flags.
        #pragma unroll
        for (int j = 0; j < 4; j++) {
            const int f = tid + 256 * j;
            while (__hip_atomic_load(&flags[f * 32],
                                     __ATOMIC_ACQUIRE, __HIP_MEMORY_SCOPE_AGENT) < t + 1) {}
        }
        __syncthreads();
    }
}

// ---------------------------------------------------------------------------
// out[o] = dot(fc_W[o,:], h) + fc_b[o]; 64 waves, 16 outputs each.
// ---------------------------------------------------------------------------
__global__ __launch_bounds__(256) void fc_kernel(
    const float* __restrict__ h, const float* __restrict__ W,
    const float* __restrict__ b, float* __restrict__ out)
{
    __shared__ float hs[HID];
    const int wv = blockIdx.x * 4 + (threadIdx.x >> 6);
    const int lane = threadIdx.x & 63;
    for (int i = threadIdx.x; i < HID; i += 256) hs[i] = h[i];
    __syncthreads();
    for (int o = wv * 16; o < wv * 16 + 16; o++) {
        float acc = 0.f;
        #pragma unroll
        for (int u = 0; u < 16; u++)
            acc += W[(size_t)o * HID + lane + 64 * u] * hs[lane + 64 * u];
        #pragma unroll
        for (int off = 32; off; off >>= 1)
            acc += __shfl_down(acc, off, 64);
        if (lane == 0) out[o] = acc + b[o];
    }
}

// ---------------------------------------------------------------------------
extern "C" void kernel_launch(void* const* d_in, const int* in_sizes, int n_in,
                              void* d_out, int out_size, void* d_ws, size_t ws_size,
                              hipStream_t stream)
{
    const float* node_feats = (const float*)d_in[0];
    const int*   node_types = (const int*)d_in[1];
    const float* W1   = (const float*)d_in[2];
    const float* b1   = (const float*)d_in[3];
    const float* W2   = (const float*)d_in[4];
    const float* b2   = (const float*)d_in[5];
    const float* Wih0 = (const float*)d_in[6];
    const float* Whh0 = (const float*)d_in[7];
    const float* bih0 = (const float*)d_in[8];
    const float* bhh0 = (const float*)d_in[9];
    const float* Wih1 = (const float*)d_in[10];
    const float* Whh1 = (const float*)d_in[11];
    const float* bih1 = (const float*)d_in[12];
    const float* bhh1 = (const float*)d_in[13];
    const float* h_init = (const float*)d_in[14];
    const float* fc_W = (const float*)d_in[15];
    const float* fc_b = (const float*)d_in[16];
    float* out = (float*)d_out;

    char* ws = (char*)d_ws;
    const size_t GI_OFF  = 0;                        // 8192*3072*4 = 100663296
    const size_t Y0_OFF  = 100663296;                // 8192*1024*4 = 33554432
    const size_t EMB_OFF = 134217728;                // 8192*512*4  = 16777216
    const size_t HB_OFF  = 150994944;                // 4096 floats = 16384
    const size_t BAR0_OFF = 151011328;               // 1024*32*4 = 131072
    const size_t BAR1_OFF = 151142400;               // 1024*32*4 = 131072

    float* gi  = (float*)(ws + GI_OFF);
    float* y0  = (float*)(ws + Y0_OFF);
    float* emb = (float*)(ws + EMB_OFF);
    float* hb  = (float*)(ws + HB_OFF);
    int* bar0  = (int*)(ws + BAR0_OFF);
    int* bar1  = (int*)(ws + BAR1_OFF);

    // Barrier flags must start at 0 (epochs count from 1); ws is poisoned.
    hipMemsetAsync(ws + BAR0_OFF, 0, 2 * 131072, stream);

    // 1. Expert MLP -> emb [8192, 512]
    mlp_kernel<<<N_NODES, 256, 0, stream>>>(node_feats, node_types, W1, b1, W2, b2, emb);

    // 2. gi0 = emb @ Wih0^T + bih0  [8192, 3072]
    gemm_bt_bias<<<dim3(G3 / BN, N_NODES / BM), 256, 0, stream>>>(
        emb, Wih0, bih0, gi, N_NODES, G3, EMB);

    // 3. layer-0 scan -> y0 [8192, 1024]
    gru_scan<<<256, 256, 0, stream>>>(gi, Whh0, bhh0, h_init, hb, hb + HID, y0, bar0, SEQ);

    // 4. gi1 = y0 @ Wih1^T + bih1  [8192, 3072]
    gemm_bt_bias<<<dim3(G3 / BN, N_NODES / BM), 256, 0, stream>>>(
        y0, Wih1, bih1, gi, N_NODES, G3, HID);

    // 5. layer-1 scan (y written to scratch, unused; final h in hb[1024..2047])
    gru_scan<<<256, 256, 0, stream>>>(gi, Whh1, bhh1, h_init + HID, hb, hb + HID, y0, bar1, SEQ);

    // 6. FC on final hidden state
    fc_kernel<<<16, 256, 0, stream>>>(hb + HID, fc_W, fc_b, out);
}

// Round 2
// 42601.404 us; speedup vs baseline: 19.5493x; 19.5493x over previous
//
#include <hip/hip_runtime.h>
#include <hip/hip_bf16.h>
#include <math.h>

typedef unsigned long long u64;

// Sizes
#define N_NODES 8192
#define IN_DIM 64
#define MLP_HID 128
#define EMB 512
#define HID 1024
#define G3 (3*HID)   // 3072
#define SEQ 8192

// ---------------------------------------------------------------------------
// Expert MLP: one block per node. h1 = relu(x@W1[t]+b1[t]); emb = h1@W2[t]+b2[t]
// ---------------------------------------------------------------------------
__global__ __launch_bounds__(256) void mlp_kernel(
    const float* __restrict__ x, const int* __restrict__ types,
    const float* __restrict__ W1, const float* __restrict__ b1,
    const float* __restrict__ W2, const float* __restrict__ b2,
    float* __restrict__ emb)
{
    __shared__ float xs[IN_DIM];
    __shared__ float h1[MLP_HID];
    const int n = blockIdx.x;
    const int ty = types[n];
    const int tid = threadIdx.x;

    if (tid < IN_DIM) xs[tid] = x[n * IN_DIM + tid];
    __syncthreads();

    if (tid < MLP_HID) {
        const float* w = W1 + (size_t)ty * IN_DIM * MLP_HID;
        float acc = b1[ty * MLP_HID + tid];
        #pragma unroll 8
        for (int k = 0; k < IN_DIM; k++)
            acc += xs[k] * w[k * MLP_HID + tid];
        h1[tid] = fmaxf(acc, 0.f);
    }
    __syncthreads();

    const float* w2 = W2 + (size_t)ty * MLP_HID * EMB;
    #pragma unroll
    for (int j = tid; j < EMB; j += 256) {
        float acc = b2[ty * EMB + j];
        #pragma unroll 8
        for (int k = 0; k < MLP_HID; k++)
            acc += h1[k] * w2[k * EMB + j];
        emb[(size_t)n * EMB + j] = acc;
    }
}

// ---------------------------------------------------------------------------
// C[M,N] = A[M,K] @ B[N,K]^T + bias[N]   (fp32, 64x64 tile, BK=16)
// ---------------------------------------------------------------------------
#define BM 64
#define BN 64
#define BK 16
__global__ __launch_bounds__(256) void gemm_bt_bias(
    const float* __restrict__ A, const float* __restrict__ B,
    const float* __restrict__ bias, float* __restrict__ C,
    int M, int N, int K)
{
    __shared__ float As[BK][BM + 1];
    __shared__ float Bs[BK][BN + 1];
    const int bm = blockIdx.y * BM, bn = blockIdx.x * BN;
    const int tid = threadIdx.x;
    const int tx = tid & 15, tyy = tid >> 4;   // 16x16 thread grid
    const int lr = tid >> 2;                   // loader row 0..63
    const int lk = (tid & 3) * 4;              // loader k offset

    float acc[4][4] = {};

    for (int k0 = 0; k0 < K; k0 += BK) {
        float4 av = *(const float4*)(A + (size_t)(bm + lr) * K + k0 + lk);
        float4 bv = *(const float4*)(B + (size_t)(bn + lr) * K + k0 + lk);
        As[lk + 0][lr] = av.x; As[lk + 1][lr] = av.y;
        As[lk + 2][lr] = av.z; As[lk + 3][lr] = av.w;
        Bs[lk + 0][lr] = bv.x; Bs[lk + 1][lr] = bv.y;
        Bs[lk + 2][lr] = bv.z; Bs[lk + 3][lr] = bv.w;
        __syncthreads();
        #pragma unroll
        for (int k = 0; k < BK; k++) {
            float a[4], b[4];
            #pragma unroll
            for (int i = 0; i < 4; i++) a[i] = As[k][tyy * 4 + i];
            #pragma unroll
            for (int j = 0; j < 4; j++) b[j] = Bs[k][tx * 4 + j];
            #pragma unroll
            for (int i = 0; i < 4; i++)
                #pragma unroll
                for (int j = 0; j < 4; j++)
                    acc[i][j] += a[i] * b[j];
        }
        __syncthreads();
    }

    #pragma unroll
    for (int i = 0; i < 4; i++) {
        const int row = bm + tyy * 4 + i;
        #pragma unroll
        for (int j = 0; j < 4; j++) {
            const int col = bn + tx * 4 + j;
            C[(size_t)row * N + col] = acc[i][j] + bias[col];
        }
    }
}

// ---------------------------------------------------------------------------
// GRU scan: 256 persistent blocks, block b owns h-dims [4b, 4b+4), one per
// wave. Whh rows live in REGISTERS (48 VGPR/thread). h is exchanged through
// a tagged-u64 double buffer: (epoch<<32)|float_bits stored with ONE relaxed
// agent-scope 8B atomic — the value is its own ready-flag, no fences.
// Polling the full 1024-entry vector each step doubles as the global barrier
// (a block can only write buf[t&1] after seeing all tags==t, which implies
// every block finished reading buf[(t-2)&1]).
// ---------------------------------------------------------------------------
__global__ __launch_bounds__(256) void gru_scan(
    const float* __restrict__ gi,    // [T, 3072]
    const float* __restrict__ Whh,   // [3072, 1024]
    const float* __restrict__ bhh,   // [3072]
    const float* __restrict__ h0,    // [1024]
    u64* __restrict__ hbuf,          // [2][1024] tagged exchange buffer
    float* __restrict__ y,           // [T, 1024] (written iff write_y)
    float* __restrict__ hout,        // [1024] final hidden state
    int T, int write_y)
{
    __shared__ float hl[HID];

    const int tid = threadIdx.x;
    const int b = blockIdx.x;
    const int wv = tid >> 6;
    const int lane = tid & 63;
    const int d = b * 4 + wv;

    // Whh rows for this wave's dim -> registers (coalesced loads).
    float wreg[3][16];
    #pragma unroll
    for (int g = 0; g < 3; g++)
        #pragma unroll
        for (int u = 0; u < 16; u++)
            wreg[g][u] = Whh[(size_t)(g * HID + d) * HID + lane + 64 * u];

    const float bh0 = bhh[d], bh1 = bhh[HID + d], bh2 = bhh[2 * HID + d];
    float hprev = h0[d];                 // only lane 0's copy is used
    float gic0 = 0.f, gic1 = 0.f, gic2 = 0.f;
    if (lane == 0) {
        gic0 = gi[d]; gic1 = gi[HID + d]; gic2 = gi[2 * HID + d];
    }

    for (int t = 0; t < T; t++) {
        // Prefetch next step's input-gate values (latency hidden by poll).
        float gin0 = 0.f, gin1 = 0.f, gin2 = 0.f;
        if (lane == 0 && t + 1 < T) {
            const float* g1 = gi + (size_t)(t + 1) * G3;
            gin0 = g1[d]; gin1 = g1[HID + d]; gin2 = g1[2 * HID + d];
        }

        // Obtain h_{t-1} into LDS.
        if (t == 0) {
            #pragma unroll
            for (int j = 0; j < 4; j++)
                hl[tid + 256 * j] = h0[tid + 256 * j];
        } else {
            const u64* src = hbuf + ((t - 1) & 1) * HID;
            #pragma unroll
            for (int j = 0; j < 4; j++) {
                const int idx = tid + 256 * j;
                u64 v = __hip_atomic_load(&src[idx], __ATOMIC_RELAXED,
                                          __HIP_MEMORY_SCOPE_AGENT);
                while ((unsigned)(v >> 32) != (unsigned)t)
                    v = __hip_atomic_load(&src[idx], __ATOMIC_RELAXED,
                                          __HIP_MEMORY_SCOPE_AGENT);
                hl[idx] = __uint_as_float((unsigned)v);
            }
        }
        __syncthreads();

        float hreg[16];
        #pragma unroll
        for (int u = 0; u < 16; u++) hreg[u] = hl[lane + 64 * u];
        __syncthreads();   // all hl reads done before next iter's poll writes

        float s0, s1, s2;
        #pragma unroll
        for (int g = 0; g < 3; g++) {
            float a0 = 0.f, a1 = 0.f, a2 = 0.f, a3 = 0.f;
            #pragma unroll
            for (int u = 0; u < 16; u += 4) {
                a0 += wreg[g][u + 0] * hreg[u + 0];
                a1 += wreg[g][u + 1] * hreg[u + 1];
                a2 += wreg[g][u + 2] * hreg[u + 2];
                a3 += wreg[g][u + 3] * hreg[u + 3];
            }
            float acc = (a0 + a1) + (a2 + a3);
            #pragma unroll
            for (int off = 32; off; off >>= 1)
                acc += __shfl_down(acc, off, 64);
            if (g == 0) s0 = acc; else if (g == 1) s1 = acc; else s2 = acc;
        }

        if (lane == 0) {
            const float r = 1.f / (1.f + expf(-(gic0 + s0 + bh0)));
            const float z = 1.f / (1.f + expf(-(gic1 + s1 + bh1)));
            const float nn = tanhf(gic2 + r * (s2 + bh2));
            const float hnew = (1.f - z) * nn + z * hprev;
            hprev = hnew;
            const u64 v = ((u64)(unsigned)(t + 1) << 32) |
                          (u64)__float_as_uint(hnew);
            __hip_atomic_store(&hbuf[(t & 1) * HID + d], v,
                               __ATOMIC_RELAXED, __HIP_MEMORY_SCOPE_AGENT);
            if (write_y) y[(size_t)t * HID + d] = hnew;
            if (t == T - 1) hout[d] = hnew;
            gic0 = gin0; gic1 = gin1; gic2 = gin2;
        }
    }
}

// ---------------------------------------------------------------------------
// out[o] = dot(fc_W[o,:], h) + fc_b[o]; 64 waves, 16 outputs each.
// ---------------------------------------------------------------------------
__global__ __launch_bounds__(256) void fc_kernel(
    const float* __restrict__ h, const float* __restrict__ W,
    const float* __restrict__ b, float* __restrict__ out)
{
    __shared__ float hs[HID];
    const int wv = blockIdx.x * 4 + (threadIdx.x >> 6);
    const int lane = threadIdx.x & 63;
    for (int i = threadIdx.x; i < HID; i += 256) hs[i] = h[i];
    __syncthreads();
    for (int o = wv * 16; o < wv * 16 + 16; o++) {
        float acc = 0.f;
        #pragma unroll
        for (int u = 0; u < 16; u++)
            acc += W[(size_t)o * HID + lane + 64 * u] * hs[lane + 64 * u];
        #pragma unroll
        for (int off = 32; off; off >>= 1)
            acc += __shfl_down(acc, off, 64);
        if (lane == 0) out[o] = acc + b[o];
    }
}

// ---------------------------------------------------------------------------
extern "C" void kernel_launch(void* const* d_in, const int* in_sizes, int n_in,
                              void* d_out, int out_size, void* d_ws, size_t ws_size,
                              hipStream_t stream)
{
    const float* node_feats = (const float*)d_in[0];
    const int*   node_types = (const int*)d_in[1];
    const float* W1   = (const float*)d_in[2];
    const float* b1   = (const float*)d_in[3];
    const float* W2   = (const float*)d_in[4];
    const float* b2   = (const float*)d_in[5];
    const float* Wih0 = (const float*)d_in[6];
    const float* Whh0 = (const float*)d_in[7];
    const float* bih0 = (const float*)d_in[8];
    const float* bhh0 = (const float*)d_in[9];
    const float* Wih1 = (const float*)d_in[10];
    const float* Whh1 = (const float*)d_in[11];
    const float* bih1 = (const float*)d_in[12];
    const float* bhh1 = (const float*)d_in[13];
    const float* h_init = (const float*)d_in[14];
    const float* fc_W = (const float*)d_in[15];
    const float* fc_b = (const float*)d_in[16];
    float* out = (float*)d_out;

    char* ws = (char*)d_ws;
    const size_t GI_OFF    = 0;                      // 8192*3072*4 = 100663296
    const size_t Y0_OFF    = 100663296;              // 8192*1024*4 = 33554432
    const size_t EMB_OFF   = 134217728;              // 8192*512*4  = 16777216
    const size_t HOUT_OFF  = 150994944;              // 1024*4      = 4096
    const size_t HBUF0_OFF = 150999040;              // 2048*8      = 16384
    const size_t HBUF1_OFF = 151015424;              // 2048*8      = 16384

    float* gi   = (float*)(ws + GI_OFF);
    float* y0   = (float*)(ws + Y0_OFF);
    float* emb  = (float*)(ws + EMB_OFF);
    float* hout = (float*)(ws + HOUT_OFF);
    u64* hbuf0  = (u64*)(ws + HBUF0_OFF);
    u64* hbuf1  = (u64*)(ws + HBUF1_OFF);
    // No memset needed: exchange buffers start 0xAA-poisoned, whose tag
    // (0xAAAAAAAA) never equals any epoch in [1, 8192]; separate buffers per
    // scan so scan 1 never sees scan 0's matching tags.

    // 1. Expert MLP -> emb [8192, 512]
    mlp_kernel<<<N_NODES, 256, 0, stream>>>(node_feats, node_types, W1, b1, W2, b2, emb);

    // 2. gi0 = emb @ Wih0^T + bih0  [8192, 3072]
    gemm_bt_bias<<<dim3(G3 / BN, N_NODES / BM), 256, 0, stream>>>(
        emb, Wih0, bih0, gi, N_NODES, G3, EMB);

    // 3. layer-0 scan -> y0 [8192, 1024]
    gru_scan<<<256, 256, 0, stream>>>(gi, Whh0, bhh0, h_init, hbuf0, y0, hout, SEQ, 1);

    // 4. gi1 = y0 @ Wih1^T + bih1  [8192, 3072]
    gemm_bt_bias<<<dim3(G3 / BN, N_NODES / BM), 256, 0, stream>>>(
        y0, Wih1, bih1, gi, N_NODES, G3, HID);

    // 5. layer-1 scan (y not written; final h -> hout)
    gru_scan<<<256, 256, 0, stream>>>(gi, Whh1, bhh1, h_init + HID, hbuf1, y0, hout, SEQ, 0);

    // 6. FC on final hidden state
    fc_kernel<<<16, 256, 0, stream>>>(hout, fc_W, fc_b, out);
}

// Round 3
// 35438.956 us; speedup vs baseline: 23.5004x; 1.2021x over previous
//
#include <hip/hip_runtime.h>
#include <hip/hip_bf16.h>
#include <math.h>

typedef unsigned long long u64;

// Sizes
#define N_NODES 8192
#define IN_DIM 64
#define MLP_HID 128
#define EMB 512
#define HID 1024
#define G3 (3*HID)   // 3072
#define SEQ 8192

// ---------------------------------------------------------------------------
// Expert MLP: one block per node. h1 = relu(x@W1[t]+b1[t]); emb = h1@W2[t]+b2[t]
// ---------------------------------------------------------------------------
__global__ __launch_bounds__(256) void mlp_kernel(
    const float* __restrict__ x, const int* __restrict__ types,
    const float* __restrict__ W1, const float* __restrict__ b1,
    const float* __restrict__ W2, const float* __restrict__ b2,
    float* __restrict__ emb)
{
    __shared__ float xs[IN_DIM];
    __shared__ float h1[MLP_HID];
    const int n = blockIdx.x;
    const int ty = types[n];
    const int tid = threadIdx.x;

    if (tid < IN_DIM) xs[tid] = x[n * IN_DIM + tid];
    __syncthreads();

    if (tid < MLP_HID) {
        const float* w = W1 + (size_t)ty * IN_DIM * MLP_HID;
        float acc = b1[ty * MLP_HID + tid];
        #pragma unroll 8
        for (int k = 0; k < IN_DIM; k++)
            acc += xs[k] * w[k * MLP_HID + tid];
        h1[tid] = fmaxf(acc, 0.f);
    }
    __syncthreads();

    const float* w2 = W2 + (size_t)ty * MLP_HID * EMB;
    #pragma unroll
    for (int j = tid; j < EMB; j += 256) {
        float acc = b2[ty * EMB + j];
        #pragma unroll 8
        for (int k = 0; k < MLP_HID; k++)
            acc += h1[k] * w2[k * EMB + j];
        emb[(size_t)n * EMB + j] = acc;
    }
}

// ---------------------------------------------------------------------------
// C[M,N] = A[M,K] @ B[N,K]^T + bias[N]   (fp32, 64x64 tile, BK=16)
// ---------------------------------------------------------------------------
#define BM 64
#define BN 64
#define BK 16
__global__ __launch_bounds__(256) void gemm_bt_bias(
    const float* __restrict__ A, const float* __restrict__ B,
    const float* __restrict__ bias, float* __restrict__ C,
    int M, int N, int K)
{
    __shared__ float As[BK][BM + 1];
    __shared__ float Bs[BK][BN + 1];
    const int bm = blockIdx.y * BM, bn = blockIdx.x * BN;
    const int tid = threadIdx.x;
    const int tx = tid & 15, tyy = tid >> 4;   // 16x16 thread grid
    const int lr = tid >> 2;                   // loader row 0..63
    const int lk = (tid & 3) * 4;              // loader k offset

    float acc[4][4] = {};

    for (int k0 = 0; k0 < K; k0 += BK) {
        float4 av = *(const float4*)(A + (size_t)(bm + lr) * K + k0 + lk);
        float4 bv = *(const float4*)(B + (size_t)(bn + lr) * K + k0 + lk);
        As[lk + 0][lr] = av.x; As[lk + 1][lr] = av.y;
        As[lk + 2][lr] = av.z; As[lk + 3][lr] = av.w;
        Bs[lk + 0][lr] = bv.x; Bs[lk + 1][lr] = bv.y;
        Bs[lk + 2][lr] = bv.z; Bs[lk + 3][lr] = bv.w;
        __syncthreads();
        #pragma unroll
        for (int k = 0; k < BK; k++) {
            float a[4], b[4];
            #pragma unroll
            for (int i = 0; i < 4; i++) a[i] = As[k][tyy * 4 + i];
            #pragma unroll
            for (int j = 0; j < 4; j++) b[j] = Bs[k][tx * 4 + j];
            #pragma unroll
            for (int i = 0; i < 4; i++)
                #pragma unroll
                for (int j = 0; j < 4; j++)
                    acc[i][j] += a[i] * b[j];
        }
        __syncthreads();
    }

    #pragma unroll
    for (int i = 0; i < 4; i++) {
        const int row = bm + tyy * 4 + i;
        #pragma unroll
        for (int j = 0; j < 4; j++) {
            const int col = bn + tx * 4 + j;
            C[(size_t)row * N + col] = acc[i][j] + bias[col];
        }
    }
}

// ---------------------------------------------------------------------------
// Fused 2-layer GRU scan, one-step skew, lockstep epochs.
// 256 blocks (1/CU, co-resident); block b's wave wv owns dim d = 4b+wv of
// BOTH layers. Epoch e (1..T+1):
//   poll hbuf0+hbuf1 for tags e-1  ->  hl0 = h0[e-2], hl1 = h1[e-3]
//   layer 0 (e<=T):  h0[e-1] = GRU(gi0[e-1], hl0)          -> hbuf0 tag e
//   layer 1 (e>=2):  h1[e-2] = GRU(Wih1@hl0 + bih1, hl1)   -> hbuf1 tag e
//   (e==1: layer 1 posts h_init[1] as tag 1)
// Polling both buffers for tags e-1 doubles as the anti-lap barrier: a block
// writes tag e (overwriting tag e-2 in the depth-2 ring) only after seeing
// every block's tag e-1, which (writes follow reads, __syncthreads) implies
// all reads of tag e-2 values completed. Tags+values share one relaxed 8B
// agent-scope atom, so no fences anywhere.
// Weights in registers: 9 rows x 16 = 144 VGPR/thread.
// ---------------------------------------------------------------------------
__global__ __launch_bounds__(256, 1) void gru_fused(
    const float* __restrict__ gi0,   // [T, 3072] precomputed layer-0 input gates (incl. bih0)
    const float* __restrict__ Whh0, const float* __restrict__ bhh0,
    const float* __restrict__ Wih1, const float* __restrict__ bih1,
    const float* __restrict__ Whh1, const float* __restrict__ bhh1,
    const float* __restrict__ h_init,   // [2, 1024]
    u64* __restrict__ hbuf0,            // [2][1024] tagged ring, layer 0
    u64* __restrict__ hbuf1,            // [2][1024] tagged ring, layer 1
    float* __restrict__ hout,           // [1024] final h1
    int T)
{
    __shared__ float hl0[HID];
    __shared__ float hl1[HID];

    const int tid = threadIdx.x;
    const int b = blockIdx.x;
    const int wv = tid >> 6;
    const int lane = tid & 63;
    const int d = b * 4 + wv;

    // Weight rows for dim d -> registers (coalesced loads).
    float w0[3][16], w1i[3][16], w1h[3][16];
    #pragma unroll
    for (int g = 0; g < 3; g++)
        #pragma unroll
        for (int u = 0; u < 16; u++) {
            w0[g][u]  = Whh0[(size_t)(g * HID + d) * HID + lane + 64 * u];
            w1i[g][u] = Wih1[(size_t)(g * HID + d) * HID + lane + 64 * u];
            w1h[g][u] = Whh1[(size_t)(g * HID + d) * HID + lane + 64 * u];
        }

    const float bh00 = bhh0[d], bh01 = bhh0[HID + d], bh02 = bhh0[2 * HID + d];
    const float bi10 = bih1[d], bi11 = bih1[HID + d], bi12 = bih1[2 * HID + d];
    const float bh10 = bhh1[d], bh11 = bhh1[HID + d], bh12 = bhh1[2 * HID + d];

    float hprev0 = 0.f, hprev1 = 0.f;
    float gc0 = 0.f, gc1 = 0.f, gc2 = 0.f;
    if (lane == 0) {
        hprev0 = h_init[d];
        hprev1 = h_init[HID + d];
        gc0 = gi0[d]; gc1 = gi0[HID + d]; gc2 = gi0[2 * HID + d];
    }

    for (int e = 1; e <= T + 1; e++) {
        // Prefetch next epoch's gi0 row (hidden under the poll).
        float gn0 = 0.f, gn1 = 0.f, gn2 = 0.f;
        if (lane == 0 && e < T) {
            const float* g = gi0 + (size_t)e * G3;
            gn0 = g[d]; gn1 = g[HID + d]; gn2 = g[2 * HID + d];
        }

        if (e == 1) {
            #pragma unroll
            for (int j = 0; j < 4; j++)
                hl0[tid + 256 * j] = h_init[tid + 256 * j];
        } else {
            const unsigned te = (unsigned)(e - 1);
            const u64* sa = hbuf0 + ((e - 1) & 1) * HID;
            const u64* sb = hbuf1 + ((e - 1) & 1) * HID;
            u64 va[4], vb[4];
            #pragma unroll
            for (int j = 0; j < 4; j++)
                va[j] = __hip_atomic_load(&sa[tid + 256 * j], __ATOMIC_RELAXED,
                                          __HIP_MEMORY_SCOPE_AGENT);
            #pragma unroll
            for (int j = 0; j < 4; j++)
                vb[j] = __hip_atomic_load(&sb[tid + 256 * j], __ATOMIC_RELAXED,
                                          __HIP_MEMORY_SCOPE_AGENT);
            #pragma unroll
            for (int j = 0; j < 4; j++)
                while ((unsigned)(va[j] >> 32) != te)
                    va[j] = __hip_atomic_load(&sa[tid + 256 * j], __ATOMIC_RELAXED,
                                              __HIP_MEMORY_SCOPE_AGENT);
            #pragma unroll
            for (int j = 0; j < 4; j++)
                while ((unsigned)(vb[j] >> 32) != te)
                    vb[j] = __hip_atomic_load(&sb[tid + 256 * j], __ATOMIC_RELAXED,
                                              __HIP_MEMORY_SCOPE_AGENT);
            #pragma unroll
            for (int j = 0; j < 4; j++) {
                hl0[tid + 256 * j] = __uint_as_float((unsigned)va[j]);
                hl1[tid + 256 * j] = __uint_as_float((unsigned)vb[j]);
            }
        }
        __syncthreads();

        float hr0[16], hr1[16];
        #pragma unroll
        for (int u = 0; u < 16; u++) hr0[u] = hl0[lane + 64 * u];
        if (e > 1) {
            #pragma unroll
            for (int u = 0; u < 16; u++) hr1[u] = hl1[lane + 64 * u];
        }
        __syncthreads();   // hl reads done before next epoch's poll overwrites

        // ---- layer 0 ----
        if (e <= T) {
            float s[3];
            #pragma unroll
            for (int g = 0; g < 3; g++) {
                float a0 = 0.f, a1 = 0.f, a2 = 0.f, a3 = 0.f;
                #pragma unroll
                for (int u = 0; u < 16; u += 4) {
                    a0 += w0[g][u + 0] * hr0[u + 0];
                    a1 += w0[g][u + 1] * hr0[u + 1];
                    a2 += w0[g][u + 2] * hr0[u + 2];
                    a3 += w0[g][u + 3] * hr0[u + 3];
                }
                float acc = (a0 + a1) + (a2 + a3);
                #pragma unroll
                for (int off = 32; off; off >>= 1)
                    acc += __shfl_down(acc, off, 64);
                s[g] = acc;
            }
            if (lane == 0) {
                const float r = 1.f / (1.f + expf(-(gc0 + s[0] + bh00)));
                const float z = 1.f / (1.f + expf(-(gc1 + s[1] + bh01)));
                const float nn = tanhf(gc2 + r * (s[2] + bh02));
                const float hnew = (1.f - z) * nn + z * hprev0;
                hprev0 = hnew;
                const u64 v = ((u64)(unsigned)e << 32) | (u64)__float_as_uint(hnew);
                __hip_atomic_store(&hbuf0[(e & 1) * HID + d], v,
                                   __ATOMIC_RELAXED, __HIP_MEMORY_SCOPE_AGENT);
                gc0 = gn0; gc1 = gn1; gc2 = gn2;
            }
        }

        // ---- layer 1 ----
        if (e == 1) {
            if (lane == 0) {
                const u64 v = ((u64)1u << 32) | (u64)__float_as_uint(hprev1);
                __hip_atomic_store(&hbuf1[HID + d], v,
                                   __ATOMIC_RELAXED, __HIP_MEMORY_SCOPE_AGENT);
            }
        } else {
            float si[3], sh[3];
            #pragma unroll
            for (int g = 0; g < 3; g++) {
                float a0 = 0.f, a1 = 0.f, a2 = 0.f, a3 = 0.f;
                float c0 = 0.f, c1 = 0.f, c2 = 0.f, c3 = 0.f;
                #pragma unroll
                for (int u = 0; u < 16; u += 4) {
                    a0 += w1i[g][u + 0] * hr0[u + 0];
                    a1 += w1i[g][u + 1] * hr0[u + 1];
                    a2 += w1i[g][u + 2] * hr0[u + 2];
                    a3 += w1i[g][u + 3] * hr0[u + 3];
                    c0 += w1h[g][u + 0] * hr1[u + 0];
                    c1 += w1h[g][u + 1] * hr1[u + 1];
                    c2 += w1h[g][u + 2] * hr1[u + 2];
                    c3 += w1h[g][u + 3] * hr1[u + 3];
                }
                float ai = (a0 + a1) + (a2 + a3);
                float ch = (c0 + c1) + (c2 + c3);
                #pragma unroll
                for (int off = 32; off; off >>= 1) {
                    ai += __shfl_down(ai, off, 64);
                    ch += __shfl_down(ch, off, 64);
                }
                si[g] = ai; sh[g] = ch;
            }
            if (lane == 0) {
                const float r = 1.f / (1.f + expf(-(si[0] + bi10 + sh[0] + bh10)));
                const float z = 1.f / (1.f + expf(-(si[1] + bi11 + sh[1] + bh11)));
                const float nn = tanhf(si[2] + bi12 + r * (sh[2] + bh12));
                const float hnew = (1.f - z) * nn + z * hprev1;
                hprev1 = hnew;
                if (e <= T) {
                    const u64 v = ((u64)(unsigned)e << 32) | (u64)__float_as_uint(hnew);
                    __hip_atomic_store(&hbuf1[(e & 1) * HID + d], v,
                                       __ATOMIC_RELAXED, __HIP_MEMORY_SCOPE_AGENT);
                } else {
                    hout[d] = hnew;   // e == T+1: final h1
                }
            }
        }
    }
}

// ---------------------------------------------------------------------------
// out[o] = dot(fc_W[o,:], h) + fc_b[o]; 64 waves, 16 outputs each.
// ---------------------------------------------------------------------------
__global__ __launch_bounds__(256) void fc_kernel(
    const float* __restrict__ h, const float* __restrict__ W,
    const float* __restrict__ b, float* __restrict__ out)
{
    __shared__ float hs[HID];
    const int wv = blockIdx.x * 4 + (threadIdx.x >> 6);
    const int lane = threadIdx.x & 63;
    for (int i = threadIdx.x; i < HID; i += 256) hs[i] = h[i];
    __syncthreads();
    for (int o = wv * 16; o < wv * 16 + 16; o++) {
        float acc = 0.f;
        #pragma unroll
        for (int u = 0; u < 16; u++)
            acc += W[(size_t)o * HID + lane + 64 * u] * hs[lane + 64 * u];
        #pragma unroll
        for (int off = 32; off; off >>= 1)
            acc += __shfl_down(acc, off, 64);
        if (lane == 0) out[o] = acc + b[o];
    }
}

// ---------------------------------------------------------------------------
extern "C" void kernel_launch(void* const* d_in, const int* in_sizes, int n_in,
                              void* d_out, int out_size, void* d_ws, size_t ws_size,
                              hipStream_t stream)
{
    const float* node_feats = (const float*)d_in[0];
    const int*   node_types = (const int*)d_in[1];
    const float* W1   = (const float*)d_in[2];
    const float* b1   = (const float*)d_in[3];
    const float* W2   = (const float*)d_in[4];
    const float* b2   = (const float*)d_in[5];
    const float* Wih0 = (const float*)d_in[6];
    const float* Whh0 = (const float*)d_in[7];
    const float* bih0 = (const float*)d_in[8];
    const float* bhh0 = (const float*)d_in[9];
    const float* Wih1 = (const float*)d_in[10];
    const float* Whh1 = (const float*)d_in[11];
    const float* bih1 = (const float*)d_in[12];
    const float* bhh1 = (const float*)d_in[13];
    const float* h_init = (const float*)d_in[14];
    const float* fc_W = (const float*)d_in[15];
    const float* fc_b = (const float*)d_in[16];
    float* out = (float*)d_out;

    char* ws = (char*)d_ws;
    const size_t GI_OFF    = 0;                      // 8192*3072*4 = 100663296
    const size_t EMB_OFF   = 100663296;              // 8192*512*4  = 16777216
    const size_t HOUT_OFF  = 117440512;              // 1024*4      = 4096
    const size_t HBUF0_OFF = 117444608;              // 2048*8      = 16384
    const size_t HBUF1_OFF = 117460992;              // 2048*8      = 16384

    float* gi   = (float*)(ws + GI_OFF);
    float* emb  = (float*)(ws + EMB_OFF);
    float* hout = (float*)(ws + HOUT_OFF);
    u64* hbuf0  = (u64*)(ws + HBUF0_OFF);
    u64* hbuf1  = (u64*)(ws + HBUF1_OFF);
    // Exchange buffers start 0xAA-poisoned each call; tag 0xAAAAAAAA never
    // equals any epoch in [1, 8193], so no memset needed.

    // 1. Expert MLP -> emb [8192, 512]
    mlp_kernel<<<N_NODES, 256, 0, stream>>>(node_feats, node_types, W1, b1, W2, b2, emb);

    // 2. gi0 = emb @ Wih0^T + bih0  [8192, 3072]
    gemm_bt_bias<<<dim3(G3 / BN, N_NODES / BM), 256, 0, stream>>>(
        emb, Wih0, bih0, gi, N_NODES, G3, EMB);

    // 3. fused 2-layer scan (layer-1 input gates computed in-kernel)
    gru_fused<<<256, 256, 0, stream>>>(gi, Whh0, bhh0, Wih1, bih1, Whh1, bhh1,
                                       h_init, hbuf0, hbuf1, hout, SEQ);

    // 4. FC on final hidden state
    fc_kernel<<<16, 256, 0, stream>>>(hout, fc_W, fc_b, out);
}

// Round 4
// 32407.736 us; speedup vs baseline: 25.6985x; 1.0935x over previous
//
#include <hip/hip_runtime.h>
#include <hip/hip_bf16.h>
#include <math.h>

typedef unsigned long long u64;

// Sizes
#define N_NODES 8192
#define IN_DIM 64
#define MLP_HID 128
#define EMB 512
#define HID 1024
#define G3 (3*HID)   // 3072
#define SEQ 8192

// ---------------------------------------------------------------------------
// Expert MLP: one block per node. h1 = relu(x@W1[t]+b1[t]); emb = h1@W2[t]+b2[t]
// ---------------------------------------------------------------------------
__global__ __launch_bounds__(256) void mlp_kernel(
    const float* __restrict__ x, const int* __restrict__ types,
    const float* __restrict__ W1, const float* __restrict__ b1,
    const float* __restrict__ W2, const float* __restrict__ b2,
    float* __restrict__ emb)
{
    __shared__ float xs[IN_DIM];
    __shared__ float h1[MLP_HID];
    const int n = blockIdx.x;
    const int ty = types[n];
    const int tid = threadIdx.x;

    if (tid < IN_DIM) xs[tid] = x[n * IN_DIM + tid];
    __syncthreads();

    if (tid < MLP_HID) {
        const float* w = W1 + (size_t)ty * IN_DIM * MLP_HID;
        float acc = b1[ty * MLP_HID + tid];
        #pragma unroll 8
        for (int k = 0; k < IN_DIM; k++)
            acc += xs[k] * w[k * MLP_HID + tid];
        h1[tid] = fmaxf(acc, 0.f);
    }
    __syncthreads();

    const float* w2 = W2 + (size_t)ty * MLP_HID * EMB;
    #pragma unroll
    for (int j = tid; j < EMB; j += 256) {
        float acc = b2[ty * EMB + j];
        #pragma unroll 8
        for (int k = 0; k < MLP_HID; k++)
            acc += h1[k] * w2[k * EMB + j];
        emb[(size_t)n * EMB + j] = acc;
    }
}

// ---------------------------------------------------------------------------
// C[M,N] = A[M,K] @ B[N,K]^T + bias[N]   (fp32, 64x64 tile, BK=16)
// ---------------------------------------------------------------------------
#define BM 64
#define BN 64
#define BK 16
__global__ __launch_bounds__(256) void gemm_bt_bias(
    const float* __restrict__ A, const float* __restrict__ B,
    const float* __restrict__ bias, float* __restrict__ C,
    int M, int N, int K)
{
    __shared__ float As[BK][BM + 1];
    __shared__ float Bs[BK][BN + 1];
    const int bm = blockIdx.y * BM, bn = blockIdx.x * BN;
    const int tid = threadIdx.x;
    const int tx = tid & 15, tyy = tid >> 4;   // 16x16 thread grid
    const int lr = tid >> 2;                   // loader row 0..63
    const int lk = (tid & 3) * 4;              // loader k offset

    float acc[4][4] = {};

    for (int k0 = 0; k0 < K; k0 += BK) {
        float4 av = *(const float4*)(A + (size_t)(bm + lr) * K + k0 + lk);
        float4 bv = *(const float4*)(B + (size_t)(bn + lr) * K + k0 + lk);
        As[lk + 0][lr] = av.x; As[lk + 1][lr] = av.y;
        As[lk + 2][lr] = av.z; As[lk + 3][lr] = av.w;
        Bs[lk + 0][lr] = bv.x; Bs[lk + 1][lr] = bv.y;
        Bs[lk + 2][lr] = bv.z; Bs[lk + 3][lr] = bv.w;
        __syncthreads();
        #pragma unroll
        for (int k = 0; k < BK; k++) {
            float a[4], b[4];
            #pragma unroll
            for (int i = 0; i < 4; i++) a[i] = As[k][tyy * 4 + i];
            #pragma unroll
            for (int j = 0; j < 4; j++) b[j] = Bs[k][tx * 4 + j];
            #pragma unroll
            for (int i = 0; i < 4; i++)
                #pragma unroll
                for (int j = 0; j < 4; j++)
                    acc[i][j] += a[i] * b[j];
        }
        __syncthreads();
    }

    #pragma unroll
    for (int i = 0; i < 4; i++) {
        const int row = bm + tyy * 4 + i;
        #pragma unroll
        for (int j = 0; j < 4; j++) {
            const int col = bn + tx * 4 + j;
            C[(size_t)row * N + col] = acc[i][j] + bias[col];
        }
    }
}

// ---------------------------------------------------------------------------
// Fused 2-layer GRU scan with counter-gated exchange.
// 256 blocks (1/CU); block b's wave wv owns dim d = 4b+wv of both layers.
// Sync per epoch: values are tagged u64 (epoch<<32 | bits) in a depth-2 ring;
// 8 monotone counters (256B-padded) gate the poll. A block: reads e-1 values
// -> computes -> stores tag-e values -> __syncthreads (drains vmcnt: stores
// visible at coherence point) -> thread0 atomicAdd(counter[b&7]). Only
// thread0 spins on the counters (8 KB/iter of poll traffic instead of 4 MB),
// then one round of tagged loads; per-word tag spin remains as a correctness
// fallback, so the counter is purely a congestion optimization.
// Anti-lap: counter(e-1)==256 implies every block read epoch-(e-2) values
// (increment follows the reads in program order + barrier), so overwriting
// ring slot (e&1) at epoch e is safe.
// ---------------------------------------------------------------------------
__global__ __launch_bounds__(256, 1) void gru_fused(
    const float* __restrict__ gi0,   // [T, 3072] layer-0 input gates (incl. bih0)
    const float* __restrict__ Whh0, const float* __restrict__ bhh0,
    const float* __restrict__ Wih1, const float* __restrict__ bih1,
    const float* __restrict__ Whh1, const float* __restrict__ bhh1,
    const float* __restrict__ h_init,   // [2, 1024]
    u64* __restrict__ hbuf0,            // [2][1024] tagged ring, layer 0
    u64* __restrict__ hbuf1,            // [2][1024] tagged ring, layer 1
    int* __restrict__ counters,         // [8] at stride 64 ints, zeroed
    float* __restrict__ hout,           // [1024] final h1
    int T)
{
    __shared__ float hl0[HID];
    __shared__ float hl1[HID];

    const int tid = threadIdx.x;
    const int b = blockIdx.x;
    const int wv = tid >> 6;
    const int lane = tid & 63;
    const int d = b * 4 + wv;

    // Weight rows for dim d (compiler may keep in regs or re-load via L1/L2;
    // latency hides under the exchange wait).
    float w0[3][16], w1i[3][16], w1h[3][16];
    #pragma unroll
    for (int g = 0; g < 3; g++)
        #pragma unroll
        for (int u = 0; u < 16; u++) {
            w0[g][u]  = Whh0[(size_t)(g * HID + d) * HID + lane + 64 * u];
            w1i[g][u] = Wih1[(size_t)(g * HID + d) * HID + lane + 64 * u];
            w1h[g][u] = Whh1[(size_t)(g * HID + d) * HID + lane + 64 * u];
        }

    const float bh00 = bhh0[d], bh01 = bhh0[HID + d], bh02 = bhh0[2 * HID + d];
    const float bi10 = bih1[d], bi11 = bih1[HID + d], bi12 = bih1[2 * HID + d];
    const float bh10 = bhh1[d], bh11 = bhh1[HID + d], bh12 = bhh1[2 * HID + d];

    float hprev0 = 0.f, hprev1 = 0.f;
    float gc0 = 0.f, gc1 = 0.f, gc2 = 0.f;
    if (lane == 0) {
        hprev0 = h_init[d];
        hprev1 = h_init[HID + d];
        gc0 = gi0[d]; gc1 = gi0[HID + d]; gc2 = gi0[2 * HID + d];
    }

    for (int e = 1; e <= T + 1; e++) {
        // Prefetch next epoch's gi0 row (hidden under the gate wait).
        float gn0 = 0.f, gn1 = 0.f, gn2 = 0.f;
        if (lane == 0 && e < T) {
            const float* g = gi0 + (size_t)e * G3;
            gn0 = g[d]; gn1 = g[HID + d]; gn2 = g[2 * HID + d];
        }

        if (e == 1) {
            #pragma unroll
            for (int j = 0; j < 4; j++)
                hl0[tid + 256 * j] = h_init[tid + 256 * j];
            __syncthreads();
        } else {
            // Gate: thread0 spins on the 8 counters; everyone else waits.
            if (tid == 0) {
                const int target = (e - 1) * 32;
                bool ready;
                do {
                    ready = true;
                    #pragma unroll
                    for (int j = 0; j < 8; j++) {
                        int c = __hip_atomic_load(&counters[j * 64],
                                                  __ATOMIC_RELAXED,
                                                  __HIP_MEMORY_SCOPE_AGENT);
                        ready &= (c >= target);
                    }
                } while (!ready);
            }
            __syncthreads();   // S1

            const unsigned te = (unsigned)(e - 1);
            const u64* sa = hbuf0 + ((e - 1) & 1) * HID;
            const u64* sb = hbuf1 + ((e - 1) & 1) * HID;
            u64 va[4], vb[4];
            #pragma unroll
            for (int j = 0; j < 4; j++)
                va[j] = __hip_atomic_load(&sa[tid + 256 * j], __ATOMIC_RELAXED,
                                          __HIP_MEMORY_SCOPE_AGENT);
            #pragma unroll
            for (int j = 0; j < 4; j++)
                vb[j] = __hip_atomic_load(&sb[tid + 256 * j], __ATOMIC_RELAXED,
                                          __HIP_MEMORY_SCOPE_AGENT);
            // Tag-check fallback (normally passes first try).
            #pragma unroll
            for (int j = 0; j < 4; j++)
                while ((unsigned)(va[j] >> 32) != te)
                    va[j] = __hip_atomic_load(&sa[tid + 256 * j], __ATOMIC_RELAXED,
                                              __HIP_MEMORY_SCOPE_AGENT);
            #pragma unroll
            for (int j = 0; j < 4; j++)
                while ((unsigned)(vb[j] >> 32) != te)
                    vb[j] = __hip_atomic_load(&sb[tid + 256 * j], __ATOMIC_RELAXED,
                                              __HIP_MEMORY_SCOPE_AGENT);
            #pragma unroll
            for (int j = 0; j < 4; j++) {
                hl0[tid + 256 * j] = __uint_as_float((unsigned)va[j]);
                hl1[tid + 256 * j] = __uint_as_float((unsigned)vb[j]);
            }
            __syncthreads();   // S2: LDS ready
        }

        float hr0[16], hr1[16];
        #pragma unroll
        for (int u = 0; u < 16; u++) hr0[u] = hl0[lane + 64 * u];
        if (e > 1) {
            #pragma unroll
            for (int u = 0; u < 16; u++) hr1[u] = hl1[lane + 64 * u];
        }
        // (hl reads complete before S3 below; next epoch's LDS writes come
        //  after next epoch's S1, so no extra barrier needed here.)

        // ---- layer 0 ----
        if (e <= T) {
            float s[3];
            #pragma unroll
            for (int g = 0; g < 3; g++) {
                float a0 = 0.f, a1 = 0.f, a2 = 0.f, a3 = 0.f;
                #pragma unroll
                for (int u = 0; u < 16; u += 4) {
                    a0 += w0[g][u + 0] * hr0[u + 0];
                    a1 += w0[g][u + 1] * hr0[u + 1];
                    a2 += w0[g][u + 2] * hr0[u + 2];
                    a3 += w0[g][u + 3] * hr0[u + 3];
                }
                float acc = (a0 + a1) + (a2 + a3);
                #pragma unroll
                for (int off = 32; off; off >>= 1)
                    acc += __shfl_down(acc, off, 64);
                s[g] = acc;
            }
            if (lane == 0) {
                const float r = 1.f / (1.f + __expf(-(gc0 + s[0] + bh00)));
                const float z = 1.f / (1.f + __expf(-(gc1 + s[1] + bh01)));
                const float nn = tanhf(gc2 + r * (s[2] + bh02));
                const float hnew = (1.f - z) * nn + z * hprev0;
                hprev0 = hnew;
                const u64 v = ((u64)(unsigned)e << 32) | (u64)__float_as_uint(hnew);
                __hip_atomic_store(&hbuf0[(e & 1) * HID + d], v,
                                   __ATOMIC_RELAXED, __HIP_MEMORY_SCOPE_AGENT);
                gc0 = gn0; gc1 = gn1; gc2 = gn2;
            }
        }

        // ---- layer 1 ----
        if (e == 1) {
            if (lane == 0) {
                const u64 v = ((u64)1u << 32) | (u64)__float_as_uint(hprev1);
                __hip_atomic_store(&hbuf1[HID + d], v,
                                   __ATOMIC_RELAXED, __HIP_MEMORY_SCOPE_AGENT);
            }
        } else {
            float si[3], sh[3];
            #pragma unroll
            for (int g = 0; g < 3; g++) {
                float a0 = 0.f, a1 = 0.f, a2 = 0.f, a3 = 0.f;
                float c0 = 0.f, c1 = 0.f, c2 = 0.f, c3 = 0.f;
                #pragma unroll
                for (int u = 0; u < 16; u += 4) {
                    a0 += w1i[g][u + 0] * hr0[u + 0];
                    a1 += w1i[g][u + 1] * hr0[u + 1];
                    a2 += w1i[g][u + 2] * hr0[u + 2];
                    a3 += w1i[g][u + 3] * hr0[u + 3];
                    c0 += w1h[g][u + 0] * hr1[u + 0];
                    c1 += w1h[g][u + 1] * hr1[u + 1];
                    c2 += w1h[g][u + 2] * hr1[u + 2];
                    c3 += w1h[g][u + 3] * hr1[u + 3];
                }
                float ai = (a0 + a1) + (a2 + a3);
                float ch = (c0 + c1) + (c2 + c3);
                #pragma unroll
                for (int off = 32; off; off >>= 1) {
                    ai += __shfl_down(ai, off, 64);
                    ch += __shfl_down(ch, off, 64);
                }
                si[g] = ai; sh[g] = ch;
            }
            if (lane == 0) {
                const float r = 1.f / (1.f + __expf(-(si[0] + bi10 + sh[0] + bh10)));
                const float z = 1.f / (1.f + __expf(-(si[1] + bi11 + sh[1] + bh11)));
                const float nn = tanhf(si[2] + bi12 + r * (sh[2] + bh12));
                const float hnew = (1.f - z) * nn + z * hprev1;
                hprev1 = hnew;
                if (e <= T) {
                    const u64 v = ((u64)(unsigned)e << 32) | (u64)__float_as_uint(hnew);
                    __hip_atomic_store(&hbuf1[(e & 1) * HID + d], v,
                                       __ATOMIC_RELAXED, __HIP_MEMORY_SCOPE_AGENT);
                } else {
                    hout[d] = hnew;   // e == T+1: final h1
                }
            }
        }

        // S3: drains the value stores (syncthreads waits vmcnt(0)) so the
        // counter increment is ordered after them at the coherence point.
        __syncthreads();
        if (tid == 0 && e <= T)
            __hip_atomic_fetch_add(&counters[(b & 7) * 64], 1,
                                   __ATOMIC_RELAXED, __HIP_MEMORY_SCOPE_AGENT);
    }
}

// ---------------------------------------------------------------------------
// out[o] = dot(fc_W[o,:], h) + fc_b[o]; 64 waves, 16 outputs each.
// ---------------------------------------------------------------------------
__global__ __launch_bounds__(256) void fc_kernel(
    const float* __restrict__ h, const float* __restrict__ W,
    const float* __restrict__ b, float* __restrict__ out)
{
    __shared__ float hs[HID];
    const int wv = blockIdx.x * 4 + (threadIdx.x >> 6);
    const int lane = threadIdx.x & 63;
    for (int i = threadIdx.x; i < HID; i += 256) hs[i] = h[i];
    __syncthreads();
    for (int o = wv * 16; o < wv * 16 + 16; o++) {
        float acc = 0.f;
        #pragma unroll
        for (int u = 0; u < 16; u++)
            acc += W[(size_t)o * HID + lane + 64 * u] * hs[lane + 64 * u];
        #pragma unroll
        for (int off = 32; off; off >>= 1)
            acc += __shfl_down(acc, off, 64);
        if (lane == 0) out[o] = acc + b[o];
    }
}

// ---------------------------------------------------------------------------
extern "C" void kernel_launch(void* const* d_in, const int* in_sizes, int n_in,
                              void* d_out, int out_size, void* d_ws, size_t ws_size,
                              hipStream_t stream)
{
    const float* node_feats = (const float*)d_in[0];
    const int*   node_types = (const int*)d_in[1];
    const float* W1   = (const float*)d_in[2];
    const float* b1   = (const float*)d_in[3];
    const float* W2   = (const float*)d_in[4];
    const float* b2   = (const float*)d_in[5];
    const float* Wih0 = (const float*)d_in[6];
    const float* Whh0 = (const float*)d_in[7];
    const float* bih0 = (const float*)d_in[8];
    const float* bhh0 = (const float*)d_in[9];
    const float* Wih1 = (const float*)d_in[10];
    const float* Whh1 = (const float*)d_in[11];
    const float* bih1 = (const float*)d_in[12];
    const float* bhh1 = (const float*)d_in[13];
    const float* h_init = (const float*)d_in[14];
    const float* fc_W = (const float*)d_in[15];
    const float* fc_b = (const float*)d_in[16];
    float* out = (float*)d_out;

    char* ws = (char*)d_ws;
    const size_t GI_OFF    = 0;                      // 8192*3072*4 = 100663296
    const size_t EMB_OFF   = 100663296;              // 8192*512*4  = 16777216
    const size_t HOUT_OFF  = 117440512;              // 1024*4      = 4096
    const size_t HBUF0_OFF = 117444608;              // 2048*8      = 16384
    const size_t HBUF1_OFF = 117460992;              // 2048*8      = 16384
    const size_t CNT_OFF   = 117477376;              // 8*64*4      = 2048

    float* gi   = (float*)(ws + GI_OFF);
    float* emb  = (float*)(ws + EMB_OFF);
    float* hout = (float*)(ws + HOUT_OFF);
    u64* hbuf0  = (u64*)(ws + HBUF0_OFF);
    u64* hbuf1  = (u64*)(ws + HBUF1_OFF);
    int* cnts   = (int*)(ws + CNT_OFF);
    // hbufs start 0xAA-poisoned: tag 0xAAAAAAAA never matches an epoch.
    // Counters must start at 0 (poison is negative -> would gate forever).
    hipMemsetAsync(ws + CNT_OFF, 0, 2048, stream);

    // 1. Expert MLP -> emb [8192, 512]
    mlp_kernel<<<N_NODES, 256, 0, stream>>>(node_feats, node_types, W1, b1, W2, b2, emb);

    // 2. gi0 = emb @ Wih0^T + bih0  [8192, 3072]
    gemm_bt_bias<<<dim3(G3 / BN, N_NODES / BM), 256, 0, stream>>>(
        emb, Wih0, bih0, gi, N_NODES, G3, EMB);

    // 3. fused 2-layer scan
    gru_fused<<<256, 256, 0, stream>>>(gi, Whh0, bhh0, Wih1, bih1, Whh1, bhh1,
                                       h_init, hbuf0, hbuf1, cnts, hout, SEQ);

    // 4. FC on final hidden state
    fc_kernel<<<16, 256, 0, stream>>>(hout, fc_W, fc_b, out);
}